// Round 1
// baseline (621.143 us; speedup 1.0000x reference)
//
#include <hip/hip_runtime.h>
#include <math.h>

#define Nn 98304
#define Ee 1572864
#define Cc 64
#define Hh 32

// ws layout (floats): dinv[Nn] | h[Nn*64] | agg[Nn*64] | flag(int)

__global__ void k_detect(const unsigned int* __restrict__ ei, int* __restrict__ flag) {
    // If edge_index is int64 (little-endian, values < 2^31), every odd 32-bit
    // word of the first entries is 0. If int32, odd words are real indices
    // (random in [0,98304) -> ~0 chance all 64 are zero).
    if (threadIdx.x == 0 && blockIdx.x == 0) {
        int all0 = 1;
        for (int i = 0; i < 64; ++i)
            if (ei[2 * i + 1] != 0u) { all0 = 0; break; }
        *flag = all0;   // 1 => int64 layout
    }
}

__device__ __forceinline__ int load_idx(const void* ei, long e, int is64) {
    if (is64) return (int)((const long long*)ei)[e];
    return ((const int*)ei)[e];
}

__global__ __launch_bounds__(256) void k_deg_init(float* __restrict__ deg) {
    int i = blockIdx.x * 256 + threadIdx.x;
    if (i < Nn) deg[i] = 1.0f;   // self-loop
}

__global__ __launch_bounds__(256) void k_deg_count(const void* __restrict__ ei,
                                                   const int* __restrict__ flag,
                                                   float* __restrict__ deg) {
    int e = blockIdx.x * 256 + threadIdx.x;
    int is64 = *flag;
    int d = load_idx(ei, (long)Ee + e, is64);   // dst row
    unsafeAtomicAdd(&deg[d], 1.0f);
}

__global__ __launch_bounds__(256) void k_dinv(float* __restrict__ deg) {
    int i = blockIdx.x * 256 + threadIdx.x;
    if (i < Nn) deg[i] = rsqrtf(deg[i]);
}

// h = state @ conv_W ; agg = h * dinv^2 (self-loop contribution, also inits agg)
__global__ __launch_bounds__(256) void k_gemm(const float* __restrict__ state,
                                              const float* __restrict__ W,
                                              const float* __restrict__ dinv,
                                              float* __restrict__ h,
                                              float* __restrict__ agg) {
    __shared__ float Wl[64 * 64];
    int t = threadIdx.x;
    #pragma unroll
    for (int i = 0; i < 16; ++i) Wl[i * 256 + t] = W[i * 256 + t];
    __syncthreads();
    int wave = t >> 6, lane = t & 63;
    int n0 = (blockIdx.x * 4 + wave) * 4;   // 4 rows per wave
    float acc0 = 0.f, acc1 = 0.f, acc2 = 0.f, acc3 = 0.f;
    const float* s0 = state + (long)n0 * 64;
    #pragma unroll 16
    for (int k = 0; k < 64; ++k) {
        float w = Wl[k * 64 + lane];
        acc0 = fmaf(s0[k],        w, acc0);
        acc1 = fmaf(s0[64 + k],   w, acc1);
        acc2 = fmaf(s0[128 + k],  w, acc2);
        acc3 = fmaf(s0[192 + k],  w, acc3);
    }
    float accs[4] = {acc0, acc1, acc2, acc3};
    #pragma unroll
    for (int r = 0; r < 4; ++r) {
        int n = n0 + r;
        h[(long)n * 64 + lane] = accs[r];
        float dv = dinv[n];
        agg[(long)n * 64 + lane] = accs[r] * dv * dv;
    }
}

// per edge: agg[dst] += h[src] * dinv[src]*dinv[dst]   (one wave per edge)
__global__ __launch_bounds__(256) void k_scatter(const void* __restrict__ ei,
                                                 const int* __restrict__ flag,
                                                 const float* __restrict__ dinv,
                                                 const float* __restrict__ h,
                                                 float* __restrict__ agg) {
    int wave = threadIdx.x >> 6, lane = threadIdx.x & 63;
    long e = (long)blockIdx.x * 4 + wave;
    int is64 = *flag;
    int s = load_idx(ei, e, is64);
    int d = load_idx(ei, (long)Ee + e, is64);
    float norm = dinv[s] * dinv[d];
    float v = h[(long)s * 64 + lane] * norm;
    unsafeAtomicAdd(&agg[(long)d * 64 + lane], v);
}

// relu(agg + conv_b) + state -> MLP 64->32->32->1 -> softplus + 1e-20
__global__ __launch_bounds__(256) void k_final(const float* __restrict__ agg,
                                               const float* __restrict__ state,
                                               const float* __restrict__ conv_b,
                                               const float* __restrict__ W1,
                                               const float* __restrict__ b1,
                                               const float* __restrict__ W2,
                                               const float* __restrict__ b2,
                                               const float* __restrict__ W3,
                                               const float* __restrict__ b3,
                                               float* __restrict__ out) {
    __shared__ float sW1[Cc * Hh];
    __shared__ float sW2[Hh * Hh];
    __shared__ float sW3[Hh], sb1[Hh], sb2[Hh], scb[Cc];
    __shared__ float sb3;
    int t = threadIdx.x;
    #pragma unroll
    for (int i = t; i < Cc * Hh; i += 256) sW1[i] = W1[i];
    #pragma unroll
    for (int i = t; i < Hh * Hh; i += 256) sW2[i] = W2[i];
    if (t < Hh) { sW3[t] = W3[t]; sb1[t] = b1[t]; sb2[t] = b2[t]; }
    if (t < Cc) scb[t] = conv_b[t];
    if (t == 0) sb3 = b3[0];
    __syncthreads();

    int n = blockIdx.x * 256 + t;
    float x[Cc];
    #pragma unroll
    for (int k = 0; k < Cc; ++k) {
        float v = agg[(long)n * 64 + k] + scb[k];
        v = fmaxf(v, 0.f);
        x[k] = v + state[(long)n * 64 + k];
    }
    float h1[Hh];
    #pragma unroll
    for (int j = 0; j < Hh; ++j) h1[j] = sb1[j];
    #pragma unroll
    for (int k = 0; k < Cc; ++k) {
        float xv = x[k];
        #pragma unroll
        for (int j = 0; j < Hh; ++j) h1[j] = fmaf(xv, sW1[k * Hh + j], h1[j]);
    }
    #pragma unroll
    for (int j = 0; j < Hh; ++j) h1[j] = fmaxf(h1[j], 0.f);

    float h2[Hh];
    #pragma unroll
    for (int j = 0; j < Hh; ++j) h2[j] = sb2[j];
    #pragma unroll
    for (int k = 0; k < Hh; ++k) {
        float xv = h1[k];
        #pragma unroll
        for (int j = 0; j < Hh; ++j) h2[j] = fmaf(xv, sW2[k * Hh + j], h2[j]);
    }
    float y = sb3;
    #pragma unroll
    for (int j = 0; j < Hh; ++j) y = fmaf(fmaxf(h2[j], 0.f), sW3[j], y);

    // stable softplus
    float sp = fmaxf(y, 0.f) + log1pf(expf(-fabsf(y)));
    out[n] = sp + 1e-20f;
}

extern "C" void kernel_launch(void* const* d_in, const int* in_sizes, int n_in,
                              void* d_out, int out_size, void* d_ws, size_t ws_size,
                              hipStream_t stream) {
    const float* state  = (const float*)d_in[0];
    const void*  ei     = d_in[1];
    const float* conv_W = (const float*)d_in[2];
    const float* conv_b = (const float*)d_in[3];
    const float* W1 = (const float*)d_in[4];
    const float* b1 = (const float*)d_in[5];
    const float* W2 = (const float*)d_in[6];
    const float* b2 = (const float*)d_in[7];
    const float* W3 = (const float*)d_in[8];
    const float* b3 = (const float*)d_in[9];
    float* out = (float*)d_out;

    float* dinv = (float*)d_ws;
    float* h    = dinv + Nn;
    float* agg  = h + (size_t)Nn * 64;
    int*   flag = (int*)(agg + (size_t)Nn * 64);

    k_detect<<<1, 64, 0, stream>>>((const unsigned int*)ei, flag);
    k_deg_init<<<Nn / 256, 256, 0, stream>>>(dinv);
    k_deg_count<<<Ee / 256, 256, 0, stream>>>(ei, flag, dinv);
    k_dinv<<<Nn / 256, 256, 0, stream>>>(dinv);
    k_gemm<<<Nn / 16, 256, 0, stream>>>(state, conv_W, dinv, h, agg);
    k_scatter<<<Ee / 4, 256, 0, stream>>>(ei, flag, dinv, h, agg);
    k_final<<<Nn / 256, 256, 0, stream>>>(agg, state, conv_b,
                                          W1, b1, W2, b2, W3, b3, out);
}

// Round 2
// 468.697 us; speedup vs baseline: 1.3253x; 1.3253x over previous
//
#include <hip/hip_runtime.h>
#include <math.h>

#define Nn 98304
#define Ee 1572864
#define Cc 64
#define Hh 32

// ws layout: dinv[Nn] f32 | g[Nn*64] f32 | agg[Nn*64] f32 | C[Nn] i32 | srcs[Ee] i32 | flag i32

__global__ void k_detect(const unsigned int* __restrict__ ei, int* __restrict__ flag) {
    // int64 little-endian indices (< 2^31) -> every odd 32-bit word is 0.
    if (threadIdx.x == 0 && blockIdx.x == 0) {
        int all0 = 1;
        for (int i = 0; i < 64; ++i)
            if (ei[2 * i + 1] != 0u) { all0 = 0; break; }
        *flag = all0;   // 1 => int64 layout
    }
}

__device__ __forceinline__ int load_idx(const void* ei, long e, int is64) {
    if (is64) return (int)((const long long*)ei)[e];
    return ((const int*)ei)[e];
}

__global__ __launch_bounds__(256) void k_zero(int* __restrict__ C) {
    int i = blockIdx.x * 256 + threadIdx.x;
    if (i < Nn) C[i] = 0;
}

__global__ __launch_bounds__(256) void k_count(const void* __restrict__ ei,
                                               const int* __restrict__ flag,
                                               int* __restrict__ C) {
    int e = blockIdx.x * 256 + threadIdx.x;
    int is64 = *flag;
    int d = load_idx(ei, (long)Ee + e, is64);
    atomicAdd(&C[d], 1);
}

// in-place exclusive scan of C (counts -> row starts); dinv = rsqrt(count+1)
__global__ __launch_bounds__(1024) void k_scan(int* __restrict__ C, float* __restrict__ dinv) {
    __shared__ int part[1024];
    const int PER = Nn / 1024;   // 96
    int t = threadIdx.x;
    int base = t * PER;
    int sum = 0;
    for (int i = 0; i < PER; ++i) sum += C[base + i];
    part[t] = sum;
    __syncthreads();
    for (int off = 1; off < 1024; off <<= 1) {
        int v = (t >= off) ? part[t - off] : 0;
        __syncthreads();
        part[t] += v;
        __syncthreads();
    }
    int running = (t == 0) ? 0 : part[t - 1];
    for (int i = 0; i < PER; ++i) {
        int v = C[base + i];
        dinv[base + i] = rsqrtf((float)(v + 1));   // +1 self-loop
        C[base + i] = running;
        running += v;
    }
}

// srcs[cursor[dst]++] = src ; afterwards C[n] == row_end(n)
__global__ __launch_bounds__(256) void k_fill(const void* __restrict__ ei,
                                              const int* __restrict__ flag,
                                              int* __restrict__ C,
                                              int* __restrict__ srcs) {
    int e = blockIdx.x * 256 + threadIdx.x;
    int is64 = *flag;
    int s = load_idx(ei, e, is64);
    int d = load_idx(ei, (long)Ee + e, is64);
    int pos = atomicAdd(&C[d], 1);
    srcs[pos] = s;
}

// g = (state @ conv_W) * dinv[row]
__global__ __launch_bounds__(256) void k_gemm(const float* __restrict__ state,
                                              const float* __restrict__ W,
                                              const float* __restrict__ dinv,
                                              float* __restrict__ g) {
    __shared__ float Wl[64 * 64];
    int t = threadIdx.x;
    #pragma unroll
    for (int i = 0; i < 16; ++i) Wl[i * 256 + t] = W[i * 256 + t];
    __syncthreads();
    int wave = t >> 6, lane = t & 63;
    int n0 = (blockIdx.x * 4 + wave) * 4;
    float acc0 = 0.f, acc1 = 0.f, acc2 = 0.f, acc3 = 0.f;
    const float* s0 = state + (long)n0 * 64;
    #pragma unroll 16
    for (int k = 0; k < 64; ++k) {
        float w = Wl[k * 64 + lane];
        acc0 = fmaf(s0[k],       w, acc0);
        acc1 = fmaf(s0[64 + k],  w, acc1);
        acc2 = fmaf(s0[128 + k], w, acc2);
        acc3 = fmaf(s0[192 + k], w, acc3);
    }
    float accs[4] = {acc0, acc1, acc2, acc3};
    #pragma unroll
    for (int r = 0; r < 4; ++r) {
        int n = n0 + r;
        g[(long)n * 64 + lane] = accs[r] * dinv[n];
    }
}

// agg[n] = dinv[n] * (g[n] + sum_{e: dst==n} g[src_e])   (one wave per node)
__global__ __launch_bounds__(256) void k_gather(const int* __restrict__ C,
                                                const int* __restrict__ srcs,
                                                const float* __restrict__ g,
                                                const float* __restrict__ dinv,
                                                float* __restrict__ agg) {
    int wave = threadIdx.x >> 6, lane = threadIdx.x & 63;
    int n = blockIdx.x * 4 + wave;
    int end = C[n];                       // post-fill: row_end(n)
    int start = (n == 0) ? 0 : C[n - 1];  // row_end(n-1) == row_start(n)
    float acc = g[(long)n * 64 + lane];   // self-loop term
    for (int base = start; base < end; base += 64) {
        int m = min(64, end - base);
        int sv = (lane < m) ? srcs[base + lane] : 0;
        int i = 0;
        for (; i + 4 <= m; i += 4) {
            int s0 = __shfl(sv, i, 64);
            int s1 = __shfl(sv, i + 1, 64);
            int s2 = __shfl(sv, i + 2, 64);
            int s3 = __shfl(sv, i + 3, 64);
            float v0 = g[(long)s0 * 64 + lane];
            float v1 = g[(long)s1 * 64 + lane];
            float v2 = g[(long)s2 * 64 + lane];
            float v3 = g[(long)s3 * 64 + lane];
            acc += (v0 + v1) + (v2 + v3);
        }
        for (; i < m; ++i) {
            int s = __shfl(sv, i, 64);
            acc += g[(long)s * 64 + lane];
        }
    }
    agg[(long)n * 64 + lane] = acc * dinv[n];
}

// relu(agg + conv_b) + state -> MLP 64->32->32->1 -> softplus + 1e-20
__global__ __launch_bounds__(256) void k_final(const float* __restrict__ agg,
                                               const float* __restrict__ state,
                                               const float* __restrict__ conv_b,
                                               const float* __restrict__ W1,
                                               const float* __restrict__ b1,
                                               const float* __restrict__ W2,
                                               const float* __restrict__ b2,
                                               const float* __restrict__ W3,
                                               const float* __restrict__ b3,
                                               float* __restrict__ out) {
    __shared__ float sW1[Cc * Hh];
    __shared__ float sW2[Hh * Hh];
    __shared__ float sW3[Hh], sb1[Hh], sb2[Hh], scb[Cc];
    __shared__ float sb3;
    int t = threadIdx.x;
    for (int i = t; i < Cc * Hh; i += 256) sW1[i] = W1[i];
    for (int i = t; i < Hh * Hh; i += 256) sW2[i] = W2[i];
    if (t < Hh) { sW3[t] = W3[t]; sb1[t] = b1[t]; sb2[t] = b2[t]; }
    if (t < Cc) scb[t] = conv_b[t];
    if (t == 0) sb3 = b3[0];
    __syncthreads();

    int n = blockIdx.x * 256 + t;
    float x[Cc];
    #pragma unroll
    for (int k = 0; k < Cc; ++k) {
        float v = agg[(long)n * 64 + k] + scb[k];
        v = fmaxf(v, 0.f);
        x[k] = v + state[(long)n * 64 + k];
    }
    float h1[Hh];
    #pragma unroll
    for (int j = 0; j < Hh; ++j) h1[j] = sb1[j];
    #pragma unroll
    for (int k = 0; k < Cc; ++k) {
        float xv = x[k];
        #pragma unroll
        for (int j = 0; j < Hh; ++j) h1[j] = fmaf(xv, sW1[k * Hh + j], h1[j]);
    }
    #pragma unroll
    for (int j = 0; j < Hh; ++j) h1[j] = fmaxf(h1[j], 0.f);

    float h2[Hh];
    #pragma unroll
    for (int j = 0; j < Hh; ++j) h2[j] = sb2[j];
    #pragma unroll
    for (int k = 0; k < Hh; ++k) {
        float xv = h1[k];
        #pragma unroll
        for (int j = 0; j < Hh; ++j) h2[j] = fmaf(xv, sW2[k * Hh + j], h2[j]);
    }
    float y = sb3;
    #pragma unroll
    for (int j = 0; j < Hh; ++j) y = fmaf(fmaxf(h2[j], 0.f), sW3[j], y);

    float sp = fmaxf(y, 0.f) + log1pf(expf(-fabsf(y)));
    out[n] = sp + 1e-20f;
}

extern "C" void kernel_launch(void* const* d_in, const int* in_sizes, int n_in,
                              void* d_out, int out_size, void* d_ws, size_t ws_size,
                              hipStream_t stream) {
    const float* state  = (const float*)d_in[0];
    const void*  ei     = d_in[1];
    const float* conv_W = (const float*)d_in[2];
    const float* conv_b = (const float*)d_in[3];
    const float* W1 = (const float*)d_in[4];
    const float* b1 = (const float*)d_in[5];
    const float* W2 = (const float*)d_in[6];
    const float* b2 = (const float*)d_in[7];
    const float* W3 = (const float*)d_in[8];
    const float* b3 = (const float*)d_in[9];
    float* out = (float*)d_out;

    float* dinv = (float*)d_ws;
    float* g    = dinv + Nn;
    float* agg  = g + (size_t)Nn * 64;
    int*   C    = (int*)(agg + (size_t)Nn * 64);
    int*   srcs = C + Nn;
    int*   flag = srcs + Ee;

    k_detect<<<1, 64, 0, stream>>>((const unsigned int*)ei, flag);
    k_zero<<<Nn / 256, 256, 0, stream>>>(C);
    k_count<<<Ee / 256, 256, 0, stream>>>(ei, flag, C);
    k_scan<<<1, 1024, 0, stream>>>(C, dinv);
    k_fill<<<Ee / 256, 256, 0, stream>>>(ei, flag, C, srcs);
    k_gemm<<<Nn / 16, 256, 0, stream>>>(state, conv_W, dinv, g);
    k_gather<<<Nn / 4, 256, 0, stream>>>(C, srcs, g, dinv, agg);
    k_final<<<Nn / 256, 256, 0, stream>>>(agg, state, conv_b,
                                          W1, b1, W2, b2, W3, b3, out);
}